// Round 6
// baseline (27.430 us; speedup 1.0000x reference)
//
#include <hip/hip_runtime.h>

// Problem constants (fixed by the reference)
#define NTOT 512   // N
#define NH   448   // N - K (identity head)
#define KK   64    // K (solved tail rows)
#define NL   30688 // strictly-lower entries in last K rows
#define DD   16    // domains
#define BB   1024  // batch
#define SLICES 16  // apply blocks per domain
#define MAXG 4     // samples per group iteration
#define LISTCAP 1024

// ws layout (bytes):
//   [0,64)            counts[16] (int)
//   [1024, 1024+64K)  lists[16][1024] (int)
//   [66560, +2MB)     Wq: [dom][(c>>2)*256 + r*4 + (c&3)] f32  (solved operator)
#define WS_LISTS_OFF 1024
#define WS_W_OFF     66560

// z_tail = W_d @ eps with W_d = (I-U_d)^{-1} [T_d | diag(s_d)] (64x512).
// L_emb[dom] row m packs T[m][0:448] at m*448+m(m-1)/2, then U[m][0:m].
// XCD locality: buildW block for (dom,cg) has blockIdx = 16 + cg*16 + dom and
// apply block (dom,slice) has blockIdx = slice*16 + dom -> both on XCD dom%8
// (round-robin dispatch heuristic), so W_d stays in that XCD's L2.

// ---------- Kernel A: 16 scan blocks + 2048 buildW blocks ----------
__global__ __launch_bounds__(256)
void fvae_prep(const int*   __restrict__ dom_idx,  // [B]
               const float* __restrict__ L_emb,    // [16, NL]
               const float* __restrict__ S_emb,    // [16, 64]
               float*       __restrict__ ws)
{
    const int bid = blockIdx.x;
    const int tid = threadIdx.x;

    if (bid < DD) {
        // ---- ballot-rank scan for domain `bid` (wave 0 only, loads prefetched)
        if (tid < 64) {
            const int dom = bid;
            int* counts = (int*)ws;
            int* lists  = (int*)((char*)ws + WS_LISTS_OFF) + dom * LISTCAP;
            int dm[BB / 64];
            #pragma unroll
            for (int t = 0; t < BB / 64; ++t) dm[t] = dom_idx[t * 64 + tid];
            int base = 0;
            #pragma unroll
            for (int t = 0; t < BB / 64; ++t) {
                const unsigned long long mt = __ballot(dm[t] == dom);
                if (dm[t] == dom) {
                    const int rank = base + __popcll(mt & ((1ull << tid) - 1ull));
                    lists[rank] = t * 64 + tid;
                }
                base += __popcll(mt);
            }
            if (tid == 0) counts[dom] = base;
        }
        return;
    }

    // ---- buildW: one wave per column; blockIdx-16 = cg*16 + dom (XCD = dom%8)
    const int t2  = bid - DD;
    const int dom = t2 & 15;
    const int cg  = t2 >> 4;
    const int w   = tid >> 6;
    const int m   = tid & 63;          // lane = row
    const int c   = cg * 4 + w;        // column 0..511 (wave-uniform)

    float* __restrict__ Wd = (float*)((char*)ws + WS_W_OFF) + (size_t)dom * (NTOT * KK);

    if (dom == 0) {                    // L=0, S=I -> W = [0 | I]
        Wd[(c >> 2) * 256 + m * 4 + (c & 3)] = (c - NH == m) ? 1.f : 0.f;
        return;
    }

    const float* __restrict__ Ld = L_emb + (size_t)dom * NL;
    const int mb = m * NH + (m * (m - 1)) / 2;

    float rhs;
    if (c < NH) {                      // wave-uniform branch
        rhs = Ld[mb + c];              // T[m][c]
    } else {
        const float sm = S_emb[dom * KK + m];
        rhs = (c - NH == m) ? sm : 0.f;
    }

    // U row m: unconditional in-bounds loads, masked (max idx mb(63)+448+62 = NL-1)
    float t[KK - 1];
    #pragma unroll
    for (int r = 0; r < KK - 1; ++r) {
        const float v = Ld[mb + NH + r];
        t[r] = (r < m) ? v : 0.f;
    }

    // forward substitution: lane r's z final by step r
    float z = rhs;
    #pragma unroll
    for (int r = 0; r < KK - 1; ++r)
        z += t[r] * __shfl(z, r);

    Wd[(c >> 2) * 256 + m * 4 + (c & 3)] = z;
}

// ---------- Kernel B: grouped matvec, 4 samples share every W load ----------
__global__ __launch_bounds__(256)
void fvae_apply(const float* __restrict__ eps,      // [B,512]
                const float* __restrict__ bias_ns,  // [16, 64]
                const float* __restrict__ bias_sh,  // [448]
                const float* __restrict__ ws,
                float*       __restrict__ out)      // [B,512]
{
    const int dom   = blockIdx.x & 15;   // XCD = dom%8, matches buildW writers
    const int slice = blockIdx.x >> 4;
    const int tid   = threadIdx.x;
    const int w     = tid >> 6;
    const int l     = tid & 63;

    __shared__ float eps_s[MAXG][NTOT];
    __shared__ float part_s[4][MAXG][KK];
    __shared__ int   idx_s[MAXG];

    const int*   counts = (const int*)ws;
    const int*   lists  = (const int*)((const char*)ws + WS_LISTS_OFF) + dom * LISTCAP;
    const float* __restrict__ Wd =
        (const float*)((const char*)ws + WS_W_OFF) + (size_t)dom * (NTOT * KK);

    const int cnt     = counts[dom];
    const int G_total = (cnt > slice) ? (cnt - 1 - slice) / SLICES + 1 : 0;
    if (G_total == 0) return;

    for (int s0 = 0; s0 < G_total; s0 += MAXG) {
        const int Gc = min(MAXG, G_total - s0);
        if (tid < Gc) idx_s[tid] = lists[slice + (s0 + tid) * SLICES];
        __syncthreads();

        // stage eps rows (float4, coalesced: 2 loads/thread)
        for (int v = tid; v < Gc * (NTOT / 4); v += 256) {
            const int g = v >> 7, q = v & 127;
            *(float4*)&eps_s[g][q * 4] =
                *(const float4*)(eps + (size_t)idx_s[g] * NTOT + q * 4);
        }
        __syncthreads();

        // head: out[:,0:448] = eps + bias_sh
        for (int v = tid; v < Gc * (NH / 4); v += 256) {
            const int g = v / 112, q = v - g * 112;
            const float4 e  = *(const float4*)&eps_s[g][q * 4];
            const float4 bs = *(const float4*)(bias_sh + q * 4);
            float4 o; o.x = e.x + bs.x; o.y = e.y + bs.y;
            o.z = e.z + bs.z; o.w = e.w + bs.w;
            *(float4*)(out + (size_t)idx_s[g] * NTOT + q * 4) = o;
        }

        // matvec: lane = output row; wave w covers q = i*4+w; 4 samples per W load
        float acc[MAXG];
        #pragma unroll
        for (int g = 0; g < MAXG; ++g) acc[g] = 0.f;
        #pragma unroll
        for (int i = 0; i < 32; ++i) {
            const int q = i * 4 + w;
            const float4 Wv = *(const float4*)(Wd + q * 256 + l * 4);  // coalesced 1KB/wave
            #pragma unroll
            for (int g = 0; g < MAXG; ++g) {                           // static idx
                const float4 e = *(const float4*)&eps_s[g][q * 4];     // LDS broadcast
                acc[g] += Wv.x * e.x + Wv.y * e.y + Wv.z * e.z + Wv.w * e.w;
            }
        }
        #pragma unroll
        for (int g = 0; g < MAXG; ++g) part_s[w][g][l] = acc[g];
        __syncthreads();

        // cross-wave reduce + tail write (tid covers 4*64 exactly)
        {
            const int g = tid >> 6, r = tid & 63;
            if (g < Gc) {
                const float z = part_s[0][g][r] + part_s[1][g][r]
                              + part_s[2][g][r] + part_s[3][g][r];
                out[(size_t)idx_s[g] * NTOT + NH + r] = z + bias_ns[dom * KK + r];
            }
        }
        __syncthreads();
    }
}

extern "C" void kernel_launch(void* const* d_in, const int* in_sizes, int n_in,
                              void* d_out, int out_size, void* d_ws, size_t ws_size,
                              hipStream_t stream) {
    const float* eps     = (const float*)d_in[0];
    const int*   dom     = (const int*)  d_in[1];
    const float* L_emb   = (const float*)d_in[2];
    const float* S_emb   = (const float*)d_in[3];
    const float* bias_ns = (const float*)d_in[4];
    const float* bias_sh = (const float*)d_in[5];
    float* out = (float*)d_out;
    float* ws  = (float*)d_ws;

    fvae_prep <<<dim3(DD + DD * 128), dim3(256), 0, stream>>>(dom, L_emb, S_emb, ws);
    fvae_apply<<<dim3(DD * SLICES),   dim3(256), 0, stream>>>(eps, bias_ns, bias_sh,
                                                              ws, out);
}